// Round 12
// baseline (492.971 us; speedup 1.0000x reference)
//
#include <hip/hip_runtime.h>
#include <math.h>

#define BDIM 2
#define CDIM 256
#define HDIM 128
#define WDIM 128
#define HW (HDIM*WDIM)
#define NPIX (BDIM*HW)

typedef float f32x4 __attribute__((ext_vector_type(4)));
typedef short bf16x8 __attribute__((ext_vector_type(8)));
typedef short bf16x4 __attribute__((ext_vector_type(4)));

__device__ __forceinline__ float geluf(float x){
  return 0.5f*x*(1.f+erff(x*0.70710678118654752f));
}
__device__ __forceinline__ unsigned short f2bf(float f){
  union{float f;unsigned u;}v; v.f=f;
  unsigned r=(v.u + 0x7FFFu + ((v.u>>16)&1u))>>16; return (unsigned short)r;
}
__device__ __forceinline__ float bf2f(unsigned short h){
  union{unsigned u;float f;}v; v.u=((unsigned)h)<<16; return v.f;
}

// ---------------- NCHW fp32 -> NHWC bf16 hi/lo pair ----------------
__global__ __launch_bounds__(256) void k_transpose(const float* __restrict__ in,
    unsigned short* __restrict__ oh, unsigned short* __restrict__ ol){
  __shared__ float tile[32][33];
  int b = blockIdx.z;
  int c0 = blockIdx.y*32;
  int p0 = blockIdx.x*32;
  int tx = threadIdx.x, ty = threadIdx.y;
  const float* src = in + (size_t)b*CDIM*HW;
  size_t dbase = (size_t)b*HW*CDIM;
  #pragma unroll
  for (int i=ty;i<32;i+=8) tile[i][tx] = src[(size_t)(c0+i)*HW + p0+tx];
  __syncthreads();
  #pragma unroll
  for (int i=ty;i<32;i+=8){
    float v = tile[tx][i];
    unsigned short h = f2bf(v);
    size_t o = dbase + (size_t)(p0+i)*CDIM + c0+tx;
    oh[o] = h;
    ol[o] = f2bf(v - bf2f(h));
  }
}

// ---------------- weight packers: fragment-linear bf16 hi/lo ----------------
__global__ void k_pack_w(const float* __restrict__ src,
    unsigned short* __restrict__ dh, unsigned short* __restrict__ dl,
    int ksn, int K, int total){
  for (int i=blockIdx.x*256+threadIdx.x; i<total; i+=gridDim.x*256){
    int r=i&7, l=(i>>3)&63, ks=(i>>9)%ksn, J=i/(ksn*512);
    int j=J*16+(l&15), k=ks*32+((l>>4)<<3)+r;
    float v = src[(size_t)j*K+k];
    unsigned short h = f2bf(v);
    dh[i]=h;
    dl[i]=f2bf(v - bf2f(h));
  }
}
__global__ void k_pack_off(const float* __restrict__ src,
    unsigned short* __restrict__ dh, unsigned short* __restrict__ dl){
  const int total=2*72*512;
  for (int i=blockIdx.x*256+threadIdx.x; i<total; i+=gridDim.x*256){
    int r=i&7, l=(i>>3)&63, ks=(i>>9)%72, J=i/(72*512);
    int oc=J*16+(l&15), k=ks*32+((l>>4)<<3)+r;
    int tap=k>>8, ch=k&255;
    float v = (oc<18) ? src[((size_t)(oc*256+ch)*3 + tap/3)*3 + (tap%3)] : 0.f;
    unsigned short h = f2bf(v);
    dh[i]=h;
    dl[i]=f2bf(v - bf2f(h));
  }
}
// depthwise weights -> fp32 [branch][tap][ch]
__global__ void k_pack_dwt(const float* __restrict__ s0, const float* __restrict__ s1,
                           const float* __restrict__ s2, float* __restrict__ dst){
  int i = blockIdx.x*256+threadIdx.x;
  if (i < 3*9*256){
    int j=i/2304, rem=i%2304, k=rem/256, c=rem%256;
    const float* s = j==0?s0:(j==1?s1:s2);
    dst[i] = s[c*9+k];
  }
}

// ---------------- offset conv via split-bf16 MFMA (3 passes) ----------------
template<int DIL>
__global__ __launch_bounds__(256) void k_offconv(
    const unsigned short* __restrict__ xh, const unsigned short* __restrict__ xl,
    const unsigned short* __restrict__ wph, const unsigned short* __restrict__ wpl,
    float* __restrict__ off){
  __shared__ float part[4*2*2*64*4];   // 16KB
  int t=threadIdx.x, l=t&63, wv=t>>6, q=l>>4;
  int p0=blockIdx.x*32;
  int b=p0>>14, prow=p0&(HW-1);
  int hh=prow>>7, w0=prow&(WDIM-1);
  const unsigned short* xbh = xh + (size_t)b*HW*CDIM;
  const unsigned short* xbl = xl + (size_t)b*HW*CDIM;
  f32x4 acc[2][2];
  #pragma unroll
  for(int mi=0;mi<2;mi++)
    #pragma unroll
    for(int pi=0;pi<2;pi++) acc[mi][pi]=(f32x4){0.f,0.f,0.f,0.f};
  for(int i=0;i<18;i++){
    int ks = wv + 4*i;
    int k0 = ks*32;
    int tap = k0>>8;
    int ky = tap/3, kx = tap%3;
    int chb = (k0&255) + q*8;
    size_t w0i = ((size_t)(0*72+ks)*64 + l)*8;
    size_t w1i = ((size_t)(1*72+ks)*64 + l)*8;
    bf16x8 a0h = *(const bf16x8*)(wph + w0i);
    bf16x8 a0l = *(const bf16x8*)(wpl + w0i);
    bf16x8 a1h = *(const bf16x8*)(wph + w1i);
    bf16x8 a1l = *(const bf16x8*)(wpl + w1i);
    int y = hh + (ky-1)*DIL;
    bf16x8 bh[2], bl[2];
    #pragma unroll
    for(int pi=0;pi<2;pi++){
      int x = w0 + pi*16 + (l&15) + (kx-1)*DIL;
      bf16x8 vh = {0,0,0,0,0,0,0,0}, vl = {0,0,0,0,0,0,0,0};
      if((unsigned)y<HDIM && (unsigned)x<WDIM){
        size_t o = ((size_t)y*WDIM + x)*CDIM + chb;
        vh = *(const bf16x8*)(xbh + o);
        vl = *(const bf16x8*)(xbl + o);
      }
      bh[pi]=vh; bl[pi]=vl;
    }
    #pragma unroll
    for(int pi=0;pi<2;pi++){
      acc[0][pi]=__builtin_amdgcn_mfma_f32_16x16x32_bf16(a0h,bh[pi],acc[0][pi],0,0,0);
      acc[0][pi]=__builtin_amdgcn_mfma_f32_16x16x32_bf16(a0l,bh[pi],acc[0][pi],0,0,0);
      acc[0][pi]=__builtin_amdgcn_mfma_f32_16x16x32_bf16(a0h,bl[pi],acc[0][pi],0,0,0);
      acc[1][pi]=__builtin_amdgcn_mfma_f32_16x16x32_bf16(a1h,bh[pi],acc[1][pi],0,0,0);
      acc[1][pi]=__builtin_amdgcn_mfma_f32_16x16x32_bf16(a1l,bh[pi],acc[1][pi],0,0,0);
      acc[1][pi]=__builtin_amdgcn_mfma_f32_16x16x32_bf16(a1h,bl[pi],acc[1][pi],0,0,0);
    }
  }
  #pragma unroll
  for(int mi=0;mi<2;mi++)
    #pragma unroll
    for(int pi=0;pi<2;pi++){
      float* pp = &part[(((wv*2+mi)*2+pi)*64 + l)*4];
      pp[0]=acc[mi][pi].x; pp[1]=acc[mi][pi].y; pp[2]=acc[mi][pi].z; pp[3]=acc[mi][pi].w;
    }
  __syncthreads();
  if(wv==0){
    #pragma unroll
    for(int mi=0;mi<2;mi++)
      #pragma unroll
      for(int pi=0;pi<2;pi++)
        #pragma unroll
        for(int r=0;r<4;r++){
          int oc = mi*16 + q*4 + r;
          if(oc<18){
            float s=0.f;
            #pragma unroll
            for(int ww=0;ww<4;ww++) s += part[(((ww*2+mi)*2+pi)*64+l)*4 + r];
            off[(size_t)(p0 + pi*16 + (l&15))*54 + oc] = s;
          }
        }
  }
}

// ---------------- 1x1 conv via split-bf16 MFMA (3 passes) ----------------
__global__ __launch_bounds__(256) void k_conv1x1(
    const unsigned short* __restrict__ xh, const unsigned short* __restrict__ xl,
    const unsigned short* __restrict__ cwph, const unsigned short* __restrict__ cwpl,
    const float* __restrict__ cb, float* __restrict__ acc){
  __shared__ float sacc[32*260];
  int t=threadIdx.x, l=t&63, wv=t>>6, q=l>>4;
  size_t p0=(size_t)blockIdx.x*32;
  f32x4 c[4][2];
  #pragma unroll
  for(int ci=0;ci<4;ci++)
    #pragma unroll
    for(int pi=0;pi<2;pi++) c[ci][pi]=(f32x4){0.f,0.f,0.f,0.f};
  for(int ks=0;ks<8;ks++){
    bf16x8 bh[2], bl[2];
    #pragma unroll
    for(int pi=0;pi<2;pi++){
      size_t o = (p0 + pi*16 + (l&15))*CDIM + ks*32 + q*8;
      bh[pi] = *(const bf16x8*)(xh + o);
      bl[pi] = *(const bf16x8*)(xl + o);
    }
    #pragma unroll
    for(int ci=0;ci<4;ci++){
      int J = wv*4+ci;
      size_t wi = ((size_t)(J*8+ks)*64+l)*8;
      bf16x8 ah = *(const bf16x8*)(cwph + wi);
      bf16x8 al = *(const bf16x8*)(cwpl + wi);
      #pragma unroll
      for(int pi=0;pi<2;pi++){
        c[ci][pi]=__builtin_amdgcn_mfma_f32_16x16x32_bf16(ah,bh[pi],c[ci][pi],0,0,0);
        c[ci][pi]=__builtin_amdgcn_mfma_f32_16x16x32_bf16(al,bh[pi],c[ci][pi],0,0,0);
        c[ci][pi]=__builtin_amdgcn_mfma_f32_16x16x32_bf16(ah,bl[pi],c[ci][pi],0,0,0);
      }
    }
  }
  #pragma unroll
  for(int ci=0;ci<4;ci++){
    int ocb = (wv*4+ci)*16 + q*4;
    float4 bb = *(const float4*)&cb[ocb];
    #pragma unroll
    for(int pi=0;pi<2;pi++){
      int pix = pi*16+(l&15);
      sacc[pix*260 + ocb+0] = c[ci][pi].x + bb.x;
      sacc[pix*260 + ocb+1] = c[ci][pi].y + bb.y;
      sacc[pix*260 + ocb+2] = c[ci][pi].z + bb.z;
      sacc[pix*260 + ocb+3] = c[ci][pi].w + bb.w;
    }
  }
  __syncthreads();
  for(int i=0;i<32;i++) acc[(p0+i)*CDIM + t] = sacc[i*260 + t];
}

// ------- fused 3-branch deformable depthwise 3x3 + LN + GELU, acc += ... -------
// samples reconstructed fp32-exact from bf16 hi/lo pair.
__global__ __launch_bounds__(256) void k_deform3(
    const unsigned short* __restrict__ xh, const unsigned short* __restrict__ xl,
    const float* __restrict__ offall, const float* __restrict__ wkt,
    const float* __restrict__ lw0, const float* __restrict__ lb0,
    const float* __restrict__ lw1, const float* __restrict__ lb1,
    const float* __restrict__ lw2, const float* __restrict__ lb2,
    float* __restrict__ acc){
  int t=threadIdx.x, l=t&63, wv=t>>6;
  int bid = blockIdx.x;
  int swz = (bid&7)*1024 + (bid>>3);
  size_t gp = (size_t)swz*4 + wv;
  int b=(int)(gp>>14); int p=(int)(gp&(HW-1)); int hh=p>>7, ww=p&(WDIM-1);
  float voff = (l<54) ? offall[gp*54 + l] : 0.f;
  const unsigned short* xbh = xh + (size_t)b*HW*CDIM;
  const unsigned short* xbl = xl + (size_t)b*HW*CDIM;
  const int h = l>>5;
  const int c0 = (l&31)*8;
  float out4[4]={0.f,0.f,0.f,0.f};
  #pragma unroll 1
  for(int j=0;j<3;j++){
    const int DIL = (j==0)?1:((j==1)?9:12);
    float d8[8];
    #pragma unroll
    for(int e=0;e<8;e++) d8[e]=0.f;
    #pragma unroll 3
    for(int k=0;k<9;k++){
      float oy = __shfl(voff, j*18+2*k);
      float ox = __shfl(voff, j*18+2*k+1);
      float py = (float)(hh+(k/3-1)*DIL)+oy;
      float px = (float)(ww+(k%3-1)*DIL)+ox;
      float y0f=floorf(py), x0f=floorf(px);
      float fy=py-y0f, fx=px-x0f;
      int iy=(int)y0f, ix=(int)x0f;
      int xx = ix + h;
      float wx = h ? fx : 1.f-fx;
      bf16x8 r0h={0,0,0,0,0,0,0,0}, r0l={0,0,0,0,0,0,0,0};
      bf16x8 r1h={0,0,0,0,0,0,0,0}, r1l={0,0,0,0,0,0,0,0};
      if((unsigned)xx < WDIM){
        if((unsigned)iy < HDIM){
          size_t o = ((size_t)iy*WDIM + xx)*CDIM + c0;
          r0h = *(const bf16x8*)(xbh + o);
          r0l = *(const bf16x8*)(xbl + o);
        }
        if((unsigned)(iy+1) < HDIM){
          size_t o = ((size_t)(iy+1)*WDIM + xx)*CDIM + c0;
          r1h = *(const bf16x8*)(xbh + o);
          r1l = *(const bf16x8*)(xbl + o);
        }
      }
      float w0 = wx*(1.f-fy), w1 = wx*fy;
      float4 wkA = *(const float4*)&wkt[(j*9+k)*256 + c0];
      float4 wkB = *(const float4*)&wkt[(j*9+k)*256 + c0 + 4];
      float wk8[8]={wkA.x,wkA.y,wkA.z,wkA.w,wkB.x,wkB.y,wkB.z,wkB.w};
      #pragma unroll
      for(int e=0;e<8;e++){
        float v0 = bf2f((unsigned short)r0h[e]) + bf2f((unsigned short)r0l[e]);
        float v1 = bf2f((unsigned short)r1h[e]) + bf2f((unsigned short)r1l[e]);
        d8[e] = fmaf(wk8[e], fmaf(w1, v1, w0*v0), d8[e]);
      }
    }
    #pragma unroll
    for(int e=0;e<8;e++) d8[e] += __shfl_xor(d8[e], 32);
    float s=0.f, sq=0.f;
    #pragma unroll
    for(int e=0;e<8;e++){ s+=d8[e]; sq+=d8[e]*d8[e]; }
    #pragma unroll
    for(int m=1;m<32;m<<=1){ s+=__shfl_xor(s,m); sq+=__shfl_xor(sq,m); }
    float u=s*(1.f/CDIM);
    float var=sq*(1.f/CDIM)-u*u;
    float rs=rsqrtf(var+1e-6f);
    float g0 = h ? d8[4] : d8[0];
    float g1 = h ? d8[5] : d8[1];
    float g2 = h ? d8[6] : d8[2];
    float g3 = h ? d8[7] : d8[3];
    const float* lw = j==0?lw0:(j==1?lw1:lw2);
    const float* lb = j==0?lb0:(j==1?lb1:lb2);
    int cb = c0 + 4*h;
    float4 wv4 = *(const float4*)&lw[cb];
    float4 bv4 = *(const float4*)&lb[cb];
    out4[0] += geluf(wv4.x*((g0-u)*rs)+bv4.x);
    out4[1] += geluf(wv4.y*((g1-u)*rs)+bv4.y);
    out4[2] += geluf(wv4.z*((g2-u)*rs)+bv4.z);
    out4[3] += geluf(wv4.w*((g3-u)*rs)+bv4.w);
  }
  float4* ap = (float4*)&acc[gp*CDIM + c0 + 4*h];
  float4 av = *ap;
  av.x+=out4[0]; av.y+=out4[1]; av.z+=out4[2]; av.w+=out4[3];
  *ap = av;
}

// ------- fused LN1 + MLP (split-bf16, 3-pass) + fp32 residual + LN2 + NCHW -------
// 16 pixels per block; hidden kept as bf16 hi/lo pair in LDS.
__global__ __launch_bounds__(256) void k_mlp(const float* __restrict__ acc,
    const unsigned short* __restrict__ w1ph, const unsigned short* __restrict__ w1pl,
    const float* __restrict__ b1,
    const unsigned short* __restrict__ w2ph, const unsigned short* __restrict__ w2pl,
    const float* __restrict__ b2,
    const float* __restrict__ n1w, const float* __restrict__ n1b,
    const float* __restrict__ n2w, const float* __restrict__ n2b,
    float* __restrict__ dout){
  __shared__ unsigned short xhs[16*256], xls[16*256];   // 8KB + 8KB
  __shared__ unsigned short hhs[16*512], hls[16*512];   // 16KB + 16KB
  __shared__ float redS[4*16], redQ[4*16];
  int t=threadIdx.x, l=t&63, wv=t>>6, q=l>>4;
  size_t p0=(size_t)blockIdx.x*16;
  // ---- LN1 (fp32) + split-bf16 pack into swizzled LDS
  {
    int px=t>>4, sg=t&15;
    const float* ar = acc + (p0+px)*CDIM + sg*16;
    float v[16];
    float s=0.f, sq=0.f;
    #pragma unroll
    for(int j=0;j<16;j+=4){
      float4 x4 = *(const float4*)&ar[j];
      v[j]=x4.x; v[j+1]=x4.y; v[j+2]=x4.z; v[j+3]=x4.w;
      s += x4.x+x4.y+x4.z+x4.w;
      sq += x4.x*x4.x+x4.y*x4.y+x4.z*x4.z+x4.w*x4.w;
    }
    #pragma unroll
    for(int m=1;m<16;m<<=1){ s += __shfl_xor(s,m); sq += __shfl_xor(sq,m); }
    float u=s*(1.f/CDIM), var=sq*(1.f/CDIM)-u*u, rs=rsqrtf(var+1e-6f);
    #pragma unroll
    for(int gi=0; gi<2; ++gi){
      bf16x8 vh, vl;
      #pragma unroll
      for(int e=0;e<8;e++){
        int c=sg*16+gi*8+e;
        float y=(v[gi*8+e]-u)*rs*n1w[c]+n1b[c];
        unsigned short hh_=f2bf(y);
        vh[e]=(short)hh_;
        vl[e]=(short)f2bf(y - bf2f(hh_));
      }
      int g = sg*2 + gi;
      int o = px*256 + ((g ^ (px&7))<<3);
      *(bf16x8*)&xhs[o] = vh;
      *(bf16x8*)&xls[o] = vl;
    }
  }
  __syncthreads();
  // ---- GEMM1 (split 3-pass): hidden[j][pix], wave wv owns j in [wv*128, wv*128+128)
  f32x4 c1[8];
  #pragma unroll
  for(int ji=0;ji<8;ji++) c1[ji]=(f32x4){0.f,0.f,0.f,0.f};
  for(int ks=0;ks<8;ks++){
    int pix=l&15;
    int g=ks*4+q;
    int o = pix*256 + ((g^(pix&7))<<3);
    bf16x8 bh=*(const bf16x8*)&xhs[o];
    bf16x8 bl=*(const bf16x8*)&xls[o];
    #pragma unroll
    for(int ji=0;ji<8;ji++){
      size_t wi = ((size_t)((wv*8+ji)*8+ks)*64+l)*8;
      bf16x8 ah=*(const bf16x8*)(w1ph + wi);
      bf16x8 al=*(const bf16x8*)(w1pl + wi);
      c1[ji]=__builtin_amdgcn_mfma_f32_16x16x32_bf16(ah,bh,c1[ji],0,0,0);
      c1[ji]=__builtin_amdgcn_mfma_f32_16x16x32_bf16(al,bh,c1[ji],0,0,0);
      c1[ji]=__builtin_amdgcn_mfma_f32_16x16x32_bf16(ah,bl,c1[ji],0,0,0);
    }
  }
  #pragma unroll
  for(int ji=0;ji<8;ji++){
    int jb=(wv*8+ji)*16 + q*4;
    float4 bb=*(const float4*)&b1[jb];
    int pix=l&15;
    float y0=geluf(c1[ji].x+bb.x);
    float y1=geluf(c1[ji].y+bb.y);
    float y2=geluf(c1[ji].z+bb.z);
    float y3=geluf(c1[ji].w+bb.w);
    bf16x4 th, tl;
    unsigned short h0=f2bf(y0); th[0]=(short)h0; tl[0]=(short)f2bf(y0-bf2f(h0));
    unsigned short h1=f2bf(y1); th[1]=(short)h1; tl[1]=(short)f2bf(y1-bf2f(h1));
    unsigned short h2=f2bf(y2); th[2]=(short)h2; tl[2]=(short)f2bf(y2-bf2f(h2));
    unsigned short h3=f2bf(y3); th[3]=(short)h3; tl[3]=(short)f2bf(y3-bf2f(h3));
    int g2=jb>>3;
    int o = pix*512 + ((g2^(pix&7))<<3) + (jb&7);
    *(bf16x4*)&hhs[o] = th;
    *(bf16x4*)&hls[o] = tl;
  }
  __syncthreads();
  // ---- GEMM2 (split 3-pass): out[ch][pix], wave wv owns ch in [wv*64, wv*64+64)
  f32x4 c2[4];
  #pragma unroll
  for(int ci=0;ci<4;ci++) c2[ci]=(f32x4){0.f,0.f,0.f,0.f};
  for(int ks=0;ks<16;ks++){
    int pix=l&15;
    int g=ks*4+q;
    int o = pix*512 + ((g^(pix&7))<<3);
    bf16x8 bh=*(const bf16x8*)&hhs[o];
    bf16x8 bl=*(const bf16x8*)&hls[o];
    #pragma unroll
    for(int ci=0;ci<4;ci++){
      size_t wi = ((size_t)((wv*4+ci)*16+ks)*64+l)*8;
      bf16x8 ah=*(const bf16x8*)(w2ph + wi);
      bf16x8 al=*(const bf16x8*)(w2pl + wi);
      c2[ci]=__builtin_amdgcn_mfma_f32_16x16x32_bf16(ah,bh,c2[ci],0,0,0);
      c2[ci]=__builtin_amdgcn_mfma_f32_16x16x32_bf16(al,bh,c2[ci],0,0,0);
      c2[ci]=__builtin_amdgcn_mfma_f32_16x16x32_bf16(ah,bl,c2[ci],0,0,0);
    }
  }
  // ---- +b2 + fp32 residual (hi+lo reconstruct), LN2 stats
  float z[4][4];
  float sp=0.f, sqp=0.f;
  int pix=l&15;
  #pragma unroll
  for(int ci=0;ci<4;ci++){
    int cb=(wv*4+ci)*16+q*4;
    float4 bb=*(const float4*)&b2[cb];
    int gr=cb>>3;
    int o = pix*256 + ((gr^(pix&7))<<3) + (cb&7);
    bf16x4 rh=*(const bf16x4*)&xhs[o];
    bf16x4 rl=*(const bf16x4*)&xls[o];
    float z0=c2[ci].x+bb.x+bf2f((unsigned short)rh[0])+bf2f((unsigned short)rl[0]);
    float z1=c2[ci].y+bb.y+bf2f((unsigned short)rh[1])+bf2f((unsigned short)rl[1]);
    float z2=c2[ci].z+bb.z+bf2f((unsigned short)rh[2])+bf2f((unsigned short)rl[2]);
    float z3=c2[ci].w+bb.w+bf2f((unsigned short)rh[3])+bf2f((unsigned short)rl[3]);
    z[ci][0]=z0; z[ci][1]=z1; z[ci][2]=z2; z[ci][3]=z3;
    sp += z0+z1+z2+z3;
    sqp += z0*z0+z1*z1+z2*z2+z3*z3;
  }
  sp += __shfl_xor(sp,16);  sp += __shfl_xor(sp,32);
  sqp += __shfl_xor(sqp,16); sqp += __shfl_xor(sqp,32);
  if(q==0){ redS[wv*16 + pix]=sp; redQ[wv*16 + pix]=sqp; }
  __syncthreads();
  float S=redS[pix]+redS[16+pix]+redS[32+pix]+redS[48+pix];
  float Q=redQ[pix]+redQ[16+pix]+redQ[32+pix]+redQ[48+pix];
  float u=S*(1.f/CDIM);
  float rs=rsqrtf(Q*(1.f/CDIM)-u*u+1e-6f);
  int bimg=(int)(p0>>14); int prow0=(int)(p0&(HW-1));
  int prow = prow0 + pix;
  #pragma unroll
  for(int ci=0;ci<4;ci++){
    int cb=(wv*4+ci)*16+q*4;
    float4 wv4=*(const float4*)&n2w[cb];
    float4 bv4=*(const float4*)&n2b[cb];
    dout[((size_t)(bimg*CDIM+cb+0))*HW + prow] = (z[ci][0]-u)*rs*wv4.x+bv4.x;
    dout[((size_t)(bimg*CDIM+cb+1))*HW + prow] = (z[ci][1]-u)*rs*wv4.y+bv4.y;
    dout[((size_t)(bimg*CDIM+cb+2))*HW + prow] = (z[ci][2]-u)*rs*wv4.z+bv4.z;
    dout[((size_t)(bimg*CDIM+cb+3))*HW + prow] = (z[ci][3]-u)*rs*wv4.w+bv4.w;
  }
}

extern "C" void kernel_launch(void* const* d_in, const int* in_sizes, int n_in,
                              void* d_out, int out_size, void* d_ws, size_t ws_size,
                              hipStream_t stream){
  const float* x = (const float*)d_in[0];
  const float* off_w[3] = {(const float*)d_in[1],(const float*)d_in[5],(const float*)d_in[9]};
  const float* def_w[3] = {(const float*)d_in[2],(const float*)d_in[6],(const float*)d_in[10]};
  const float* bw[3]    = {(const float*)d_in[3],(const float*)d_in[7],(const float*)d_in[11]};
  const float* bbr[3]   = {(const float*)d_in[4],(const float*)d_in[8],(const float*)d_in[12]};
  const float* conv_w = (const float*)d_in[13];
  const float* conv_b = (const float*)d_in[14];
  const float* n1w = (const float*)d_in[15];
  const float* n1b = (const float*)d_in[16];
  const float* n2w = (const float*)d_in[17];
  const float* n2b = (const float*)d_in[18];
  const float* w1  = (const float*)d_in[19];
  const float* b1  = (const float*)d_in[20];
  const float* w2  = (const float*)d_in[21];
  const float* b2  = (const float*)d_in[22];

  // fp32 region first, then bf16 arrays (all 16B aligned)
  float* acc    = (float*)d_ws;                            // 8,388,608 f32
  float* offall = acc + (size_t)NPIX*CDIM;                 // 1,769,472 f32
  float* wkt    = offall + (size_t)NPIX*54;                // 6,912 f32
  unsigned short* xh   = (unsigned short*)(wkt + 6912);    // NPIX*256
  unsigned short* xl   = xh + (size_t)NPIX*CDIM;
  unsigned short* w1ph = xl + (size_t)NPIX*CDIM;           // 131072 each
  unsigned short* w1pl = w1ph + 131072;
  unsigned short* w2ph = w1pl + 131072;
  unsigned short* w2pl = w2ph + 131072;
  unsigned short* cwph = w2pl + 131072;                    // 65536 each
  unsigned short* cwpl = cwph + 65536;
  unsigned short* woph = cwpl + 65536;                     // 3*73728 each
  unsigned short* wopl = woph + 221184;

  k_transpose<<<dim3(HW/32, CDIM/32, BDIM), dim3(32,8), 0, stream>>>(x, xh, xl);
  k_pack_w<<<512, 256, 0, stream>>>(w1, w1ph, w1pl, 8, 256, 131072);
  k_pack_w<<<512, 256, 0, stream>>>(w2, w2ph, w2pl, 16, 512, 131072);
  k_pack_w<<<256, 256, 0, stream>>>(conv_w, cwph, cwpl, 8, 256, 65536);
  k_pack_off<<<288, 256, 0, stream>>>(off_w[0], woph + 0,      wopl + 0);
  k_pack_off<<<288, 256, 0, stream>>>(off_w[1], woph + 73728,  wopl + 73728);
  k_pack_off<<<288, 256, 0, stream>>>(off_w[2], woph + 147456, wopl + 147456);
  k_pack_dwt<<<27, 256, 0, stream>>>(def_w[0], def_w[1], def_w[2], wkt);
  k_offconv<1> <<<NPIX/32, 256, 0, stream>>>(xh, xl, woph + 0,      wopl + 0,      offall + 0);
  k_offconv<9> <<<NPIX/32, 256, 0, stream>>>(xh, xl, woph + 73728,  wopl + 73728,  offall + 18);
  k_offconv<12><<<NPIX/32, 256, 0, stream>>>(xh, xl, woph + 147456, wopl + 147456, offall + 36);
  k_conv1x1<<<NPIX/32, 256, 0, stream>>>(xh, xl, cwph, cwpl, conv_b, acc);
  k_deform3<<<NPIX/4, 256, 0, stream>>>(xh, xl, offall, wkt,
      bw[0], bbr[0], bw[1], bbr[1], bw[2], bbr[2], acc);
  k_mlp<<<NPIX/16, 256, 0, stream>>>(acc, w1ph, w1pl, b1, w2ph, w2pl, b2,
      n1w, n1b, n2w, n2b, (float*)d_out);
}